// Round 7
// baseline (535.998 us; speedup 1.0000x reference)
//
#include <hip/hip_runtime.h>

#define K_RECENT 10

typedef float f32x4 __attribute__((ext_vector_type(4)));
typedef int   i32x4 __attribute__((ext_vector_type(4)));

// ---------------------------------------------------------------------------
// global -> LDS direct DMA (16 B per lane). LDS dest is wave-uniform base;
// HW scatters lane*16. Global src is per-lane.
// ---------------------------------------------------------------------------
__device__ __forceinline__ void glds16(const float* g, float* l) {
    __builtin_amdgcn_global_load_lds(
        (const __attribute__((address_space(1))) unsigned int*)(const void*)g,
        (__attribute__((address_space(3))) unsigned int*)(void*)l,
        16, 0, 0);
}

// ---------------------------------------------------------------------------
// Kernel 1: user_pref[b, :] = masked mean of region_emb over last-10 valid
// positions. One block per b, 128 threads (= D).
// ---------------------------------------------------------------------------
__global__ void pref_kernel(const int* __restrict__ user_seq,
                            const int* __restrict__ user_seq_len,
                            const int* __restrict__ poi_region_id,
                            const float* __restrict__ region_emb,
                            float* __restrict__ pref,
                            int S, int D) {
    int b = blockIdx.x;
    int tid = threadIdx.x;
    __shared__ int rids[K_RECENT];

    int len = user_seq_len[b];
    if (tid < K_RECENT) {
        int pos = len - K_RECENT + tid;
        int r = -1;
        if (pos >= 0) {
            int poi = user_seq[b * S + pos];
            r = poi_region_id[poi];
        }
        rids[tid] = r;
    }
    __syncthreads();

    float acc = 0.f;
    int cnt = 0;
#pragma unroll
    for (int j = 0; j < K_RECENT; ++j) {
        int r = rids[j];
        if (r >= 0) {
            ++cnt;
            acc += region_emb[r * D + tid];
        }
    }
    float c = (cnt > 0) ? (float)cnt : 1.f;
    pref[b * D + tid] = acc / c;
}

// ---------------------------------------------------------------------------
// Kernel 2 (coalesced): scores[b, r] = pref[b] . region_emb[r], D = 128.
// Block: 256 threads -> 64 r x 8 b. region_emb tile staged in LDS with
// coalesced 128B-run loads (old version: 64-way line-fragmented per wave).
// ---------------------------------------------------------------------------
#define SC_RT 64
#define SC_BT 8
__global__ void scores_kernel2(const float* __restrict__ pref,
                               const float* __restrict__ region_emb,
                               float* __restrict__ scores,
                               int R) {
    __shared__ float et[SC_RT][36];   // 32 d + 4 pad (bank spread)
    __shared__ float pt[SC_BT][32];

    int tid = threadIdx.x;
    int r0 = blockIdx.x * SC_RT;
    int b0 = blockIdx.y * SC_BT;
    int rl = tid & 63;
    int bb = tid >> 6;                // 0..3

    float acc0 = 0.f, acc1 = 0.f;

#pragma unroll
    for (int t = 0; t < 4; ++t) {     // d-tiles of 32 floats
        // stage emb tile: 512 float4, 2 per thread, 128B contiguous runs
#pragma unroll
        for (int j = 0; j < 2; ++j) {
            int fi = j * 256 + tid;
            int rr = fi >> 3, d4 = fi & 7;
            int rg = min(r0 + rr, R - 1);
            f32x4 v = *(const f32x4*)&region_emb[(size_t)rg * 128 + t * 32 + d4 * 4];
            *(f32x4*)&et[rr][d4 * 4] = v;
        }
        if (tid < 64) {
            int br = tid >> 3, d4 = tid & 7;
            *(f32x4*)&pt[br][d4 * 4] =
                *(const f32x4*)&pref[(size_t)(b0 + br) * 128 + t * 32 + d4 * 4];
        }
        __syncthreads();
#pragma unroll
        for (int d4 = 0; d4 < 8; ++d4) {
            f32x4 e  = *(const f32x4*)&et[rl][d4 * 4];
            f32x4 pa = *(const f32x4*)&pt[bb][d4 * 4];      // wave-uniform bcast
            f32x4 pb = *(const f32x4*)&pt[bb + 4][d4 * 4];
            acc0 = fmaf(e.x, pa.x, fmaf(e.y, pa.y, fmaf(e.z, pa.z, fmaf(e.w, pa.w, acc0))));
            acc1 = fmaf(e.x, pb.x, fmaf(e.y, pb.y, fmaf(e.z, pb.z, fmaf(e.w, pb.w, acc1))));
        }
        __syncthreads();
    }
    int r = r0 + rl;
    if (r < R) {
        scores[(size_t)(b0 + bb) * R + r]     = acc0;
        scores[(size_t)(b0 + bb + 4) * R + r] = acc1;
    }
}

// ---------------------------------------------------------------------------
// Kernel 3 (staged): out[b,l] = pred[b,l] + alpha * srow[rid[l]].
// pred streamed via global_load_lds into a wave-private 8-buffer LDS ring
// (bypasses the per-CU L1 miss-tracking path); rid in an 8-deep inline-asm
// register ring. Counted s_waitcnt vmcnt(N) keeps 4 tiles (4 KB/wave) in
// flight. No barriers in the loop (wave-private buffers).
// ---------------------------------------------------------------------------
#define OUT_BLOCK 256
#define OUT_F     4
#define MAX_R     2048

__global__ void __launch_bounds__(256)
out_kernel_staged(const float* __restrict__ pred,
                  const float* __restrict__ scores,
                  const int* __restrict__ rid,
                  const float* __restrict__ alpha_p,
                  float* __restrict__ out,
                  int L, int R, int CPB, int FS, int rounds) {
    __shared__ float srow[MAX_R];
    __shared__ float lds_pred[4][8][256];   // [wave][buf][64 lanes x 4 floats]

    int b    = blockIdx.y;
    int tid  = threadIdx.x;
    int w    = tid >> 6;
    int lane = tid & 63;
    float alpha = alpha_p[0];

    // Cooperative fill of the score row.
    {
        const float* g = scores + (size_t)b * R;
        int R4 = R >> 2;
        for (int i = tid; i < R4; i += OUT_BLOCK)
            ((f32x4*)srow)[i] = ((const f32x4*)g)[i];
        for (int i = (R4 << 2) + tid; i < R; i += OUT_BLOCK)
            srow[i] = g[i];
    }
    __syncthreads();

    int base = blockIdx.x * CPB;            // float4 units
    const i32x4* rp = (const i32x4*)rid + base;
    const f32x4* pp = (const f32x4*)(pred + (size_t)b * L) + base;
    f32x4*       op = (f32x4*)(out + (size_t)b * L) + base;

    i32x4 r0, r1, r2, r3, r4, r5, r6, r7;

    // Prologue: stage tiles 0..3 (pred -> LDS bufs 0..3, rid -> regs r0..r3).
#define PRO(J, RREG) do {                                                   \
        glds16((const float*)(pp + ((J) * 256 + tid)),                      \
               &lds_pred[w][(J)][0]);                                       \
        { const i32x4* _ra = rp + ((J) * 256 + tid);                        \
          asm volatile("global_load_dwordx4 %0, %1, off"                    \
                       : "=v"(RREG) : "v"(_ra) : "memory"); }               \
    } while (0)
    PRO(0, r0); PRO(1, r1); PRO(2, r2); PRO(3, r3);
#undef PRO

#define OUT_ITER(J, WN, LOADR, CURR) do {                                   \
        glds16((const float*)(ppk + (((J) + 4) * 256 + tid)),               \
               &lds_pred[w][((J) + 4) & 7][0]);                             \
        { const i32x4* _ra = rpk + (((J) + 4) * 256 + tid);                 \
          asm volatile("global_load_dwordx4 %0, %1, off"                    \
                       : "=v"(LOADR) : "v"(_ra) : "memory"); }              \
        asm volatile("s_waitcnt vmcnt(" #WN ")" ::: "memory");              \
        __builtin_amdgcn_sched_barrier(0);                                  \
        { f32x4 _pv = *(const f32x4*)&lds_pred[w][(J) & 7][lane * 4];       \
          i32x4 _c = CURR;                                                  \
          f32x4 _o;                                                         \
          _o.x = fmaf(alpha, srow[_c.x], _pv.x);                            \
          _o.y = fmaf(alpha, srow[_c.y], _pv.y);                            \
          _o.z = fmaf(alpha, srow[_c.z], _pv.z);                            \
          _o.w = fmaf(alpha, srow[_c.w], _pv.w);                            \
          __builtin_nontemporal_store(_o, opk + (J) * 256 + tid); }         \
    } while (0)

    const f32x4* ppk = pp;
    const i32x4* rpk = rp;
    f32x4*       opk = op;
    for (int k8 = 0; k8 < FS; k8 += 8) {
        OUT_ITER(0,  8, r4, r0);
        OUT_ITER(1,  9, r5, r1);
        OUT_ITER(2, 10, r6, r2);
        OUT_ITER(3, 11, r7, r3);
        OUT_ITER(4, 12, r0, r4);
        OUT_ITER(5, 12, r1, r5);
        OUT_ITER(6, 12, r2, r6);
        OUT_ITER(7, 12, r3, r7);
        ppk += 8 * 256; rpk += 8 * 256; opk += 8 * 256;
    }
#undef OUT_ITER

    // Epilogue: tiles FS..FS+3 are staged (bufs 0..3, regs r0..r3).
    asm volatile("s_waitcnt vmcnt(0)" ::: "memory");
    __builtin_amdgcn_sched_barrier(0);
#define OUT_EPI(J, CURR) do {                                               \
        f32x4 _pv = *(const f32x4*)&lds_pred[w][(J) & 7][lane * 4];         \
        i32x4 _c = CURR;                                                    \
        f32x4 _o;                                                           \
        _o.x = fmaf(alpha, srow[_c.x], _pv.x);                              \
        _o.y = fmaf(alpha, srow[_c.y], _pv.y);                              \
        _o.z = fmaf(alpha, srow[_c.z], _pv.z);                              \
        _o.w = fmaf(alpha, srow[_c.w], _pv.w);                              \
        __builtin_nontemporal_store(_o, opk + (J) * 256 + tid);             \
    } while (0)
    OUT_EPI(0, r0); OUT_EPI(1, r1); OUT_EPI(2, r2); OUT_EPI(3, r3);
#undef OUT_EPI

    // Masked tail within the chunk (CPB - rounds*256 float4 elements).
    int i = rounds * 256 + tid;
    if (i < CPB) {
        i32x4 c = rp[i];
        f32x4 p = pp[i];
        f32x4 o;
        o.x = fmaf(alpha, srow[c.x], p.x);
        o.y = fmaf(alpha, srow[c.y], p.y);
        o.z = fmaf(alpha, srow[c.z], p.z);
        o.w = fmaf(alpha, srow[c.w], p.w);
        __builtin_nontemporal_store(o, op + i);
    }
}

// ---------------------------------------------------------------------------
// Fallback out kernel (round-6 version) for shapes the staged kernel
// doesn't cover.
// ---------------------------------------------------------------------------
#define PIPE 4
__global__ void out_kernel_pipe(const float* __restrict__ pred,
                                const float* __restrict__ scores,
                                const int* __restrict__ rid,
                                const float* __restrict__ alpha_p,
                                float* __restrict__ out,
                                int L4, int L, int R, int CPB) {
    __shared__ float srow[MAX_R];
    int b   = blockIdx.y;
    int tid = threadIdx.x;
    float alpha = alpha_p[0];

    const float* g = scores + (size_t)b * R;
    int R4 = R >> 2;
    for (int i = tid; i < R4; i += OUT_BLOCK)
        ((f32x4*)srow)[i] = ((const f32x4*)g)[i];
    for (int i = (R4 << 2) + tid; i < R; i += OUT_BLOCK)
        srow[i] = g[i];
    __syncthreads();

    int base = blockIdx.x * CPB;
    int n = min(CPB, L4 - base);
    if (n <= 0) return;

    const i32x4* rp = (const i32x4*)rid + base;
    const f32x4* pp = (const f32x4*)(pred + (size_t)b * L) + base;
    f32x4*       op = (f32x4*)(out + (size_t)b * L) + base;

    int rounds  = n >> 8;
    int batches = rounds / PIPE;

    for (int kb = 0; kb < batches; ++kb) {
        int i0 = kb * (PIPE * OUT_BLOCK) + tid;
        i32x4 r4v[PIPE];
        f32x4 p[PIPE];
#pragma unroll
        for (int j = 0; j < PIPE; ++j) r4v[j] = rp[i0 + j * OUT_BLOCK];
#pragma unroll
        for (int j = 0; j < PIPE; ++j) p[j]  = pp[i0 + j * OUT_BLOCK];
#pragma unroll
        for (int j = 0; j < PIPE; ++j) {
            f32x4 o;
            o.x = fmaf(alpha, srow[r4v[j].x], p[j].x);
            o.y = fmaf(alpha, srow[r4v[j].y], p[j].y);
            o.z = fmaf(alpha, srow[r4v[j].z], p[j].z);
            o.w = fmaf(alpha, srow[r4v[j].w], p[j].w);
            __builtin_nontemporal_store(o, &op[i0 + j * OUT_BLOCK]);
        }
    }
    for (int k = batches * PIPE; k < rounds; ++k) {
        int i = k * OUT_BLOCK + tid;
        i32x4 c = rp[i];
        f32x4 p = pp[i];
        f32x4 o;
        o.x = fmaf(alpha, srow[c.x], p.x);
        o.y = fmaf(alpha, srow[c.y], p.y);
        o.z = fmaf(alpha, srow[c.z], p.z);
        o.w = fmaf(alpha, srow[c.w], p.w);
        __builtin_nontemporal_store(o, &op[i]);
    }
    int i = rounds * OUT_BLOCK + tid;
    if (i < n) {
        i32x4 c = rp[i];
        f32x4 p = pp[i];
        f32x4 o;
        o.x = fmaf(alpha, srow[c.x], p.x);
        o.y = fmaf(alpha, srow[c.y], p.y);
        o.z = fmaf(alpha, srow[c.z], p.z);
        o.w = fmaf(alpha, srow[c.w], p.w);
        __builtin_nontemporal_store(o, &op[i]);
    }
}

__global__ void out_kernel_scalar(const float* __restrict__ pred,
                                  const float* __restrict__ scores,
                                  const int* __restrict__ rid,
                                  const float* __restrict__ alpha_p,
                                  float* __restrict__ out,
                                  int l0, int L, int R) {
    int b = blockIdx.y;
    int l = l0 + blockIdx.x * blockDim.x + threadIdx.x;
    if (l >= L) return;
    float alpha = alpha_p[0];
    out[(size_t)b * L + l] =
        fmaf(alpha, scores[(size_t)b * R + rid[l]], pred[(size_t)b * L + l]);
}

extern "C" void kernel_launch(void* const* d_in, const int* in_sizes, int n_in,
                              void* d_out, int out_size, void* d_ws, size_t ws_size,
                              hipStream_t stream) {
    const float* pred_base     = (const float*)d_in[0];
    const int*   user_seq      = (const int*)d_in[1];
    const int*   user_seq_len  = (const int*)d_in[2];
    const int*   poi_region_id = (const int*)d_in[3];
    const float* region_emb    = (const float*)d_in[4];
    const float* alpha         = (const float*)d_in[5];
    float*       out           = (float*)d_out;

    const int B = in_sizes[2];              // 1024
    const int S = in_sizes[1] / B;          // 200
    const int L = in_sizes[3];              // 50000
    const int D = 128;
    const int R = in_sizes[4] / D;          // 2000

    float* scores = (float*)d_ws;
    float* pref   = scores + (size_t)B * R;

    // 1) user_pref
    pref_kernel<<<B, D, 0, stream>>>(user_seq, user_seq_len, poi_region_id,
                                     region_emb, pref, S, D);

    // 2) scores[B,R] — coalesced tiled version (needs B % 8 == 0)
    if ((B % SC_BT) == 0) {
        dim3 g2((R + SC_RT - 1) / SC_RT, B / SC_BT);
        scores_kernel2<<<g2, 256, 0, stream>>>(pref, region_emb, scores, R);
    }

    // 3) output
    int L4 = L / 4;
    if (L4 > 0) {
        bool eq_chunks = (L4 % OUT_F) == 0;
        int CPB   = eq_chunks ? L4 / OUT_F : (L4 + OUT_F - 1) / OUT_F;
        int rounds = CPB >> 8;
        int FS     = rounds - 4;
        bool staged_ok = (R <= MAX_R) && eq_chunks && FS >= 8 && (FS % 8) == 0;
        if (staged_ok) {
            dim3 g3(OUT_F, B);
            out_kernel_staged<<<g3, OUT_BLOCK, 0, stream>>>(
                pred_base, scores, poi_region_id, alpha, out, L, R, CPB, FS, rounds);
        } else if (R <= MAX_R) {
            dim3 g3(OUT_F, B);
            out_kernel_pipe<<<g3, OUT_BLOCK, 0, stream>>>(
                pred_base, scores, poi_region_id, alpha, out, L4, L, R, CPB);
        } else {
            dim3 gt(((L4 * 4) + 255) / 256, B);
            out_kernel_scalar<<<gt, 256, 0, stream>>>(
                pred_base, scores, poi_region_id, alpha, out, 0, L4 * 4, R);
        }
    }
    int tail = L - L4 * 4;
    if (tail > 0) {
        dim3 gt(1, B);
        out_kernel_scalar<<<gt, 64, 0, stream>>>(pred_base, scores, poi_region_id,
                                                 alpha, out, L4 * 4, L, R);
    }
}

// Round 8
// 95.862 us; speedup vs baseline: 5.5913x; 5.5913x over previous
//
#include <hip/hip_runtime.h>

#define K_RECENT 10

typedef float f32x4 __attribute__((ext_vector_type(4)));
typedef int   i32x4 __attribute__((ext_vector_type(4)));

// ---------------------------------------------------------------------------
// global -> LDS direct DMA (16 B per lane). LDS dest is wave-uniform base;
// HW scatters lane*16. Global src is per-lane.
// ---------------------------------------------------------------------------
__device__ __forceinline__ void glds16(const float* g, float* l) {
    __builtin_amdgcn_global_load_lds(
        (const __attribute__((address_space(1))) unsigned int*)(const void*)g,
        (__attribute__((address_space(3))) unsigned int*)(void*)l,
        16, 0, 0);
}

// ---------------------------------------------------------------------------
// Kernel 1: user_pref[b, :] = masked mean of region_emb over last-10 valid
// positions. One block per b, 128 threads (= D).
// ---------------------------------------------------------------------------
__global__ void pref_kernel(const int* __restrict__ user_seq,
                            const int* __restrict__ user_seq_len,
                            const int* __restrict__ poi_region_id,
                            const float* __restrict__ region_emb,
                            float* __restrict__ pref,
                            int S, int D) {
    int b = blockIdx.x;
    int tid = threadIdx.x;
    __shared__ int rids[K_RECENT];

    int len = user_seq_len[b];
    if (tid < K_RECENT) {
        int pos = len - K_RECENT + tid;
        int r = -1;
        if (pos >= 0) {
            int poi = user_seq[b * S + pos];
            r = poi_region_id[poi];
        }
        rids[tid] = r;
    }
    __syncthreads();

    float acc = 0.f;
    int cnt = 0;
#pragma unroll
    for (int j = 0; j < K_RECENT; ++j) {
        int r = rids[j];
        if (r >= 0) {
            ++cnt;
            acc += region_emb[r * D + tid];
        }
    }
    float c = (cnt > 0) ? (float)cnt : 1.f;
    pref[b * D + tid] = acc / c;
}

// ---------------------------------------------------------------------------
// Kernel 2 (round-6 proven version): scores[b, r] = pref[b] . region_emb[r]
// Block: 256 threads, 8 batch rows (pref tile in LDS, float4 broadcast reads)
// x one 256-wide slab of r. region_emb is 1 MB -> L2-resident.
// ---------------------------------------------------------------------------
__global__ void scores_kernel(const float* __restrict__ pref,
                              const float* __restrict__ region_emb,
                              float* __restrict__ scores,
                              int R) {
    const int BT = 8;          // batch rows per block
    const int D  = 128;
    __shared__ float pl[BT * D];

    int tid = threadIdx.x;
    int b0  = blockIdx.y * BT;

    ((f32x4*)pl)[tid] = ((const f32x4*)(pref + (size_t)b0 * D))[tid];
    __syncthreads();

    int r = blockIdx.x * blockDim.x + tid;
    if (r >= R) return;

    float acc[BT];
#pragma unroll
    for (int bb = 0; bb < BT; ++bb) acc[bb] = 0.f;

    const f32x4* erow = (const f32x4*)(region_emb + (size_t)r * D);
#pragma unroll 8
    for (int d4 = 0; d4 < D / 4; ++d4) {
        f32x4 e = erow[d4];
#pragma unroll
        for (int bb = 0; bb < BT; ++bb) {
            f32x4 pv = *reinterpret_cast<const f32x4*>(&pl[bb * D + d4 * 4]);
            acc[bb] = fmaf(e.x, pv.x,
                      fmaf(e.y, pv.y,
                      fmaf(e.z, pv.z,
                      fmaf(e.w, pv.w, acc[bb]))));
        }
    }
#pragma unroll
    for (int bb = 0; bb < BT; ++bb)
        scores[(size_t)(b0 + bb) * R + r] = acc[bb];
}

// ---------------------------------------------------------------------------
// Kernel 3 (staged): out[b,l] = pred[b,l] + alpha * srow[rid[l]].
// pred streamed via global_load_lds into a wave-private 8-buffer LDS ring
// (bypasses the per-CU L1 miss-tracking path); rid in an 8-deep inline-asm
// register ring. Counted s_waitcnt vmcnt(N) keeps 4 tiles (4 KB/wave) in
// flight. No barriers in the loop (wave-private buffers).
// ---------------------------------------------------------------------------
#define OUT_BLOCK 256
#define OUT_F     4
#define MAX_R     2048

__global__ void __launch_bounds__(256)
out_kernel_staged(const float* __restrict__ pred,
                  const float* __restrict__ scores,
                  const int* __restrict__ rid,
                  const float* __restrict__ alpha_p,
                  float* __restrict__ out,
                  int L, int R, int CPB, int FS, int rounds) {
    __shared__ float srow[MAX_R];
    __shared__ float lds_pred[4][8][256];   // [wave][buf][64 lanes x 4 floats]

    int b    = blockIdx.y;
    int tid  = threadIdx.x;
    int w    = tid >> 6;
    int lane = tid & 63;
    float alpha = alpha_p[0];

    // Cooperative fill of the score row.
    {
        const float* g = scores + (size_t)b * R;
        int R4 = R >> 2;
        for (int i = tid; i < R4; i += OUT_BLOCK)
            ((f32x4*)srow)[i] = ((const f32x4*)g)[i];
        for (int i = (R4 << 2) + tid; i < R; i += OUT_BLOCK)
            srow[i] = g[i];
    }
    __syncthreads();

    int base = blockIdx.x * CPB;            // float4 units
    const i32x4* rp = (const i32x4*)rid + base;
    const f32x4* pp = (const f32x4*)(pred + (size_t)b * L) + base;
    f32x4*       op = (f32x4*)(out + (size_t)b * L) + base;

    i32x4 r0, r1, r2, r3, r4, r5, r6, r7;

    // Prologue: stage tiles 0..3 (pred -> LDS bufs 0..3, rid -> regs r0..r3).
#define PRO(J, RREG) do {                                                   \
        glds16((const float*)(pp + ((J) * 256 + tid)),                      \
               &lds_pred[w][(J)][0]);                                       \
        { const i32x4* _ra = rp + ((J) * 256 + tid);                        \
          asm volatile("global_load_dwordx4 %0, %1, off"                    \
                       : "=v"(RREG) : "v"(_ra) : "memory"); }               \
    } while (0)
    PRO(0, r0); PRO(1, r1); PRO(2, r2); PRO(3, r3);
#undef PRO

#define OUT_ITER(J, WN, LOADR, CURR) do {                                   \
        glds16((const float*)(ppk + (((J) + 4) * 256 + tid)),               \
               &lds_pred[w][((J) + 4) & 7][0]);                             \
        { const i32x4* _ra = rpk + (((J) + 4) * 256 + tid);                 \
          asm volatile("global_load_dwordx4 %0, %1, off"                    \
                       : "=v"(LOADR) : "v"(_ra) : "memory"); }              \
        asm volatile("s_waitcnt vmcnt(" #WN ")" ::: "memory");              \
        __builtin_amdgcn_sched_barrier(0);                                  \
        { f32x4 _pv = *(const f32x4*)&lds_pred[w][(J) & 7][lane * 4];       \
          i32x4 _c = CURR;                                                  \
          f32x4 _o;                                                         \
          _o.x = fmaf(alpha, srow[_c.x], _pv.x);                            \
          _o.y = fmaf(alpha, srow[_c.y], _pv.y);                            \
          _o.z = fmaf(alpha, srow[_c.z], _pv.z);                            \
          _o.w = fmaf(alpha, srow[_c.w], _pv.w);                            \
          __builtin_nontemporal_store(_o, opk + (J) * 256 + tid); }         \
    } while (0)

    const f32x4* ppk = pp;
    const i32x4* rpk = rp;
    f32x4*       opk = op;
    for (int k8 = 0; k8 < FS; k8 += 8) {
        OUT_ITER(0,  8, r4, r0);
        OUT_ITER(1,  9, r5, r1);
        OUT_ITER(2, 10, r6, r2);
        OUT_ITER(3, 11, r7, r3);
        OUT_ITER(4, 12, r0, r4);
        OUT_ITER(5, 12, r1, r5);
        OUT_ITER(6, 12, r2, r6);
        OUT_ITER(7, 12, r3, r7);
        ppk += 8 * 256; rpk += 8 * 256; opk += 8 * 256;
    }
#undef OUT_ITER

    // Epilogue: tiles FS..FS+3 are staged (bufs 0..3, regs r0..r3).
    asm volatile("s_waitcnt vmcnt(0)" ::: "memory");
    __builtin_amdgcn_sched_barrier(0);
#define OUT_EPI(J, CURR) do {                                               \
        f32x4 _pv = *(const f32x4*)&lds_pred[w][(J) & 7][lane * 4];         \
        i32x4 _c = CURR;                                                    \
        f32x4 _o;                                                           \
        _o.x = fmaf(alpha, srow[_c.x], _pv.x);                              \
        _o.y = fmaf(alpha, srow[_c.y], _pv.y);                              \
        _o.z = fmaf(alpha, srow[_c.z], _pv.z);                              \
        _o.w = fmaf(alpha, srow[_c.w], _pv.w);                              \
        __builtin_nontemporal_store(_o, opk + (J) * 256 + tid);             \
    } while (0)
    OUT_EPI(0, r0); OUT_EPI(1, r1); OUT_EPI(2, r2); OUT_EPI(3, r3);
#undef OUT_EPI

    // Masked tail within the chunk (CPB - rounds*256 float4 elements).
    int i = rounds * 256 + tid;
    if (i < CPB) {
        i32x4 c = rp[i];
        f32x4 p = pp[i];
        f32x4 o;
        o.x = fmaf(alpha, srow[c.x], p.x);
        o.y = fmaf(alpha, srow[c.y], p.y);
        o.z = fmaf(alpha, srow[c.z], p.z);
        o.w = fmaf(alpha, srow[c.w], p.w);
        __builtin_nontemporal_store(o, op + i);
    }
}

// ---------------------------------------------------------------------------
// Fallback out kernel (round-6 version) for shapes the staged kernel
// doesn't cover.
// ---------------------------------------------------------------------------
#define PIPE 4
__global__ void out_kernel_pipe(const float* __restrict__ pred,
                                const float* __restrict__ scores,
                                const int* __restrict__ rid,
                                const float* __restrict__ alpha_p,
                                float* __restrict__ out,
                                int L4, int L, int R, int CPB) {
    __shared__ float srow[MAX_R];
    int b   = blockIdx.y;
    int tid = threadIdx.x;
    float alpha = alpha_p[0];

    const float* g = scores + (size_t)b * R;
    int R4 = R >> 2;
    for (int i = tid; i < R4; i += OUT_BLOCK)
        ((f32x4*)srow)[i] = ((const f32x4*)g)[i];
    for (int i = (R4 << 2) + tid; i < R; i += OUT_BLOCK)
        srow[i] = g[i];
    __syncthreads();

    int base = blockIdx.x * CPB;
    int n = min(CPB, L4 - base);
    if (n <= 0) return;

    const i32x4* rp = (const i32x4*)rid + base;
    const f32x4* pp = (const f32x4*)(pred + (size_t)b * L) + base;
    f32x4*       op = (f32x4*)(out + (size_t)b * L) + base;

    int rounds  = n >> 8;
    int batches = rounds / PIPE;

    for (int kb = 0; kb < batches; ++kb) {
        int i0 = kb * (PIPE * OUT_BLOCK) + tid;
        i32x4 r4v[PIPE];
        f32x4 p[PIPE];
#pragma unroll
        for (int j = 0; j < PIPE; ++j) r4v[j] = rp[i0 + j * OUT_BLOCK];
#pragma unroll
        for (int j = 0; j < PIPE; ++j) p[j]  = pp[i0 + j * OUT_BLOCK];
#pragma unroll
        for (int j = 0; j < PIPE; ++j) {
            f32x4 o;
            o.x = fmaf(alpha, srow[r4v[j].x], p[j].x);
            o.y = fmaf(alpha, srow[r4v[j].y], p[j].y);
            o.z = fmaf(alpha, srow[r4v[j].z], p[j].z);
            o.w = fmaf(alpha, srow[r4v[j].w], p[j].w);
            __builtin_nontemporal_store(o, &op[i0 + j * OUT_BLOCK]);
        }
    }
    for (int k = batches * PIPE; k < rounds; ++k) {
        int i = k * OUT_BLOCK + tid;
        i32x4 c = rp[i];
        f32x4 p = pp[i];
        f32x4 o;
        o.x = fmaf(alpha, srow[c.x], p.x);
        o.y = fmaf(alpha, srow[c.y], p.y);
        o.z = fmaf(alpha, srow[c.z], p.z);
        o.w = fmaf(alpha, srow[c.w], p.w);
        __builtin_nontemporal_store(o, &op[i]);
    }
    int i = rounds * OUT_BLOCK + tid;
    if (i < n) {
        i32x4 c = rp[i];
        f32x4 p = pp[i];
        f32x4 o;
        o.x = fmaf(alpha, srow[c.x], p.x);
        o.y = fmaf(alpha, srow[c.y], p.y);
        o.z = fmaf(alpha, srow[c.z], p.z);
        o.w = fmaf(alpha, srow[c.w], p.w);
        __builtin_nontemporal_store(o, &op[i]);
    }
}

__global__ void out_kernel_scalar(const float* __restrict__ pred,
                                  const float* __restrict__ scores,
                                  const int* __restrict__ rid,
                                  const float* __restrict__ alpha_p,
                                  float* __restrict__ out,
                                  int l0, int L, int R) {
    int b = blockIdx.y;
    int l = l0 + blockIdx.x * blockDim.x + threadIdx.x;
    if (l >= L) return;
    float alpha = alpha_p[0];
    out[(size_t)b * L + l] =
        fmaf(alpha, scores[(size_t)b * R + rid[l]], pred[(size_t)b * L + l]);
}

extern "C" void kernel_launch(void* const* d_in, const int* in_sizes, int n_in,
                              void* d_out, int out_size, void* d_ws, size_t ws_size,
                              hipStream_t stream) {
    const float* pred_base     = (const float*)d_in[0];
    const int*   user_seq      = (const int*)d_in[1];
    const int*   user_seq_len  = (const int*)d_in[2];
    const int*   poi_region_id = (const int*)d_in[3];
    const float* region_emb    = (const float*)d_in[4];
    const float* alpha         = (const float*)d_in[5];
    float*       out           = (float*)d_out;

    const int B = in_sizes[2];              // 1024
    const int S = in_sizes[1] / B;          // 200
    const int L = in_sizes[3];              // 50000
    const int D = 128;
    const int R = in_sizes[4] / D;          // 2000

    float* scores = (float*)d_ws;
    float* pref   = scores + (size_t)B * R;

    // 1) user_pref
    pref_kernel<<<B, D, 0, stream>>>(user_seq, user_seq_len, poi_region_id,
                                     region_emb, pref, S, D);

    // 2) scores[B,R] — round-6 proven version
    dim3 g2((R + 255) / 256, B / 8);
    scores_kernel<<<g2, 256, 0, stream>>>(pref, region_emb, scores, R);

    // 3) output
    int L4 = L / 4;
    if (L4 > 0) {
        bool eq_chunks = (L4 % OUT_F) == 0;
        int CPB   = eq_chunks ? L4 / OUT_F : (L4 + OUT_F - 1) / OUT_F;
        int rounds = CPB >> 8;
        int FS     = rounds - 4;
        bool staged_ok = (R <= MAX_R) && eq_chunks && FS >= 8 && (FS % 8) == 0;
        if (staged_ok) {
            dim3 g3(OUT_F, B);
            out_kernel_staged<<<g3, OUT_BLOCK, 0, stream>>>(
                pred_base, scores, poi_region_id, alpha, out, L, R, CPB, FS, rounds);
        } else if (R <= MAX_R) {
            dim3 g3(OUT_F, B);
            out_kernel_pipe<<<g3, OUT_BLOCK, 0, stream>>>(
                pred_base, scores, poi_region_id, alpha, out, L4, L, R, CPB);
        } else {
            dim3 gt(((L4 * 4) + 255) / 256, B);
            out_kernel_scalar<<<gt, 256, 0, stream>>>(
                pred_base, scores, poi_region_id, alpha, out, 0, L4 * 4, R);
        }
    }
    int tail = L - L4 * 4;
    if (tail > 0) {
        dim3 gt(1, B);
        out_kernel_scalar<<<gt, 64, 0, stream>>>(pred_base, scores, poi_region_id,
                                                 alpha, out, L4 * 4, L, R);
    }
}